// Round 1
// baseline (1022.506 us; speedup 1.0000x reference)
//
#include <hip/hip_runtime.h>

// EideticLinearLayer: out = X @ W^T + bias ; idx = searchsorted_left(quantiles[col], wx)
// X: [16384, 256] f32, W: [4096, 256] f32, bias: [4096], quantiles: [4096, 31]
// d_out: [16384*4096] out floats, then [16384*4096] index floats.

#define B_DIM 16384
#define K_DIM 256
#define N_DIM 4096
#define NQ 31

#define BM 128
#define BN 128
#define BK 16
#define TM 8
#define TN 8
// 256 threads: tx (0..15) covers N in steps of 8, ty (0..15) covers M in steps of 8.

__global__ __launch_bounds__(256)
void eidetic_fused(const float* __restrict__ X,
                   const float* __restrict__ W,
                   const float* __restrict__ bias,
                   const float* __restrict__ Q,
                   float* __restrict__ out,
                   float* __restrict__ idxo)
{
    __shared__ float As[BK][BM];     // 8 KiB, transposed A tile
    __shared__ float Bs[BK][BN];     // 8 KiB, transposed B tile
    __shared__ float Qs[BN * NQ];    // 15.5 KiB, quantiles for this block's columns

    const int tid = threadIdx.x;
    const int tx = tid & 15;
    const int ty = tid >> 4;
    const int m0 = blockIdx.x * BM;
    const int n0 = blockIdx.y * BN;

    // tile-load mapping: 256 threads load 128 rows x 16 cols (x2 row halves) as float4
    const int lr = tid >> 2;          // 0..63
    const int lc = (tid & 3) << 2;    // 0,4,8,12

    float acc[TM][TN];
#pragma unroll
    for (int i = 0; i < TM; ++i)
#pragma unroll
        for (int j = 0; j < TN; ++j) acc[i][j] = 0.f;

    const float* Aptr = X + (size_t)(m0 + lr) * K_DIM + lc;
    const float* Bptr = W + (size_t)(n0 + lr) * K_DIM + lc;

    for (int k0 = 0; k0 < K_DIM; k0 += BK) {
        const float4 a0 = *(const float4*)(Aptr + k0);
        const float4 a1 = *(const float4*)(Aptr + (size_t)64 * K_DIM + k0);
        const float4 b0 = *(const float4*)(Bptr + k0);
        const float4 b1 = *(const float4*)(Bptr + (size_t)64 * K_DIM + k0);
        __syncthreads();  // previous compute phase done reading LDS
        As[lc + 0][lr] = a0.x;  As[lc + 1][lr] = a0.y;  As[lc + 2][lr] = a0.z;  As[lc + 3][lr] = a0.w;
        As[lc + 0][lr + 64] = a1.x;  As[lc + 1][lr + 64] = a1.y;  As[lc + 2][lr + 64] = a1.z;  As[lc + 3][lr + 64] = a1.w;
        Bs[lc + 0][lr] = b0.x;  Bs[lc + 1][lr] = b0.y;  Bs[lc + 2][lr] = b0.z;  Bs[lc + 3][lr] = b0.w;
        Bs[lc + 0][lr + 64] = b1.x;  Bs[lc + 1][lr + 64] = b1.y;  Bs[lc + 2][lr + 64] = b1.z;  Bs[lc + 3][lr + 64] = b1.w;
        __syncthreads();
#pragma unroll
        for (int k = 0; k < BK; ++k) {
            float a[TM], b[TN];
            *(float4*)&a[0] = *(const float4*)&As[k][ty * TM];
            *(float4*)&a[4] = *(const float4*)&As[k][ty * TM + 4];
            *(float4*)&b[0] = *(const float4*)&Bs[k][tx * TN];
            *(float4*)&b[4] = *(const float4*)&Bs[k][tx * TN + 4];
#pragma unroll
            for (int i = 0; i < TM; ++i)
#pragma unroll
                for (int j = 0; j < TN; ++j)
                    acc[i][j] = fmaf(a[i], b[j], acc[i][j]);
        }
    }

    // stage this block's quantiles [128 cols x 31] into LDS (flat copy, coalesced)
    __syncthreads();
    for (int t = tid; t < BN * NQ; t += 256) Qs[t] = Q[(size_t)n0 * NQ + t];
    __syncthreads();

    float biasr[TN];
#pragma unroll
    for (int j = 0; j < TN; ++j) biasr[j] = bias[n0 + tx * TN + j];

    float cnt[TM][TN];
#pragma unroll
    for (int i = 0; i < TM; ++i)
#pragma unroll
        for (int j = 0; j < TN; ++j) cnt[i][j] = 0.f;

    // searchsorted side='left': index = count of bounds strictly < val
    for (int t = 0; t < NQ; ++t) {
        float qv[TN];
#pragma unroll
        for (int j = 0; j < TN; ++j) qv[j] = Qs[(tx * TN + j) * NQ + t];
#pragma unroll
        for (int i = 0; i < TM; ++i)
#pragma unroll
            for (int j = 0; j < TN; ++j)
                cnt[i][j] += (qv[j] < acc[i][j]) ? 1.0f : 0.0f;
    }

#pragma unroll
    for (int i = 0; i < TM; ++i) {
        const size_t row = (size_t)(m0 + ty * TM + i) * N_DIM + n0 + tx * TN;
        float4 o0, o1, c0, c1;
        o0.x = acc[i][0] + biasr[0];  o0.y = acc[i][1] + biasr[1];
        o0.z = acc[i][2] + biasr[2];  o0.w = acc[i][3] + biasr[3];
        o1.x = acc[i][4] + biasr[4];  o1.y = acc[i][5] + biasr[5];
        o1.z = acc[i][6] + biasr[6];  o1.w = acc[i][7] + biasr[7];
        c0.x = cnt[i][0]; c0.y = cnt[i][1]; c0.z = cnt[i][2]; c0.w = cnt[i][3];
        c1.x = cnt[i][4]; c1.y = cnt[i][5]; c1.z = cnt[i][6]; c1.w = cnt[i][7];
        *(float4*)(out + row)      = o0;
        *(float4*)(out + row + 4)  = o1;
        *(float4*)(idxo + row)     = c0;
        *(float4*)(idxo + row + 4) = c1;
    }
}

extern "C" void kernel_launch(void* const* d_in, const int* in_sizes, int n_in,
                              void* d_out, int out_size, void* d_ws, size_t ws_size,
                              hipStream_t stream) {
    const float* x    = (const float*)d_in[0];
    const float* w    = (const float*)d_in[1];
    const float* bias = (const float*)d_in[2];
    const float* q    = (const float*)d_in[3];
    float* out  = (float*)d_out;
    float* idxo = out + (size_t)B_DIM * N_DIM;

    dim3 grid(B_DIM / BM, N_DIM / BN);
    hipLaunchKernelGGL(eidetic_fused, grid, dim3(256), 0, stream,
                       x, w, bias, q, out, idxo);
}